// Round 5
// baseline (264.014 us; speedup 1.0000x reference)
//
#include <hip/hip_runtime.h>
#include <hip/hip_bf16.h>

#define BT 4
#define TT 4096
#define DM 1024
#define DH 64
#define NRE 17   // 2*MAX_REL+1

using bf16 = __hip_bfloat16;
typedef __attribute__((ext_vector_type(8))) short short8;
typedef __attribute__((ext_vector_type(4))) short short4v;
typedef __attribute__((ext_vector_type(4))) float float4v;

static __device__ __forceinline__ short8 load8(const bf16* p) {
    return *reinterpret_cast<const short8*>(p);
}
static __device__ __forceinline__ short bfbits(float x) {
    return (short)__bfloat16_as_ushort(__float2bfloat16(x));
}
static __device__ __forceinline__ short8 pack8(float4v a, float4v b) {
    short8 r;
    r[0] = bfbits(a[0]); r[1] = bfbits(a[1]); r[2] = bfbits(a[2]); r[3] = bfbits(a[3]);
    r[4] = bfbits(b[0]); r[5] = bfbits(b[1]); r[6] = bfbits(b[2]); r[7] = bfbits(b[3]);
    return r;
}

// ---------------------------------------------------------------------------
// Kernel 0: W prep — concat Wq|Wk|Wv (192x1024) f32 -> bf16 once.
// ---------------------------------------------------------------------------
__global__ __launch_bounds__(256) void w_prep(
    const float* __restrict__ Wq, const float* __restrict__ Wk,
    const float* __restrict__ Wv, bf16* __restrict__ Wb)
{
    const int row = blockIdx.x;          // 0..191
    const float* src = (row < 64) ? &Wq[(size_t)row * DM]
                     : (row < 128) ? &Wk[(size_t)(row - 64) * DM]
                                   : &Wv[(size_t)(row - 128) * DM];
    float4v v = reinterpret_cast<const float4v*>(src)[threadIdx.x];
    short4v s;
    s[0] = bfbits(v[0]); s[1] = bfbits(v[1]); s[2] = bfbits(v[2]); s[3] = bfbits(v[3]);
    *reinterpret_cast<short4v*>(&Wb[(size_t)row * DM + 4 * threadIdx.x]) = s;
}

// ---------------------------------------------------------------------------
// Kernel 1: QKV GEMM — no LDS staging, register double-buffered direct loads.
// 512 blocks x 512 thr. Block = 32 rows; wave = (row-half 16) x (48-col
// quarter). Per k-step: 2 b128 x-loads (f32) + 3 b128 W-loads (bf16) + 3 MFMA,
// next step's loads issued before current compute (depth-1 pipeline, no
// barriers in the K-loop). V epilogue transposes through a 4.3 KB LDS tile
// so Vt stores are coalesced 8B instead of scattered 2B.
// ---------------------------------------------------------------------------
__global__ __launch_bounds__(512, 4) void qkv_gemm(
    const float* __restrict__ x, const bf16* __restrict__ Wb,
    bf16* __restrict__ Qb, bf16* __restrict__ Kb, bf16* __restrict__ Vt)
{
    __shared__ bf16 Vls[64][34];         // [d][t_local], pad 32->34

    const int w     = threadIdx.x >> 6;  // 0..7
    const int lane  = threadIdx.x & 63;
    const int quad  = lane >> 4;
    const int l16   = lane & 15;
    const int half  = w & 1;
    const int colq  = w >> 1;            // 0..3
    const int row0  = blockIdx.x * 32;

    const float* xp = &x[(size_t)(row0 + 16 * half + l16) * DM + quad * 8];
    const bf16*  W0 = &Wb[(size_t)(48 * colq + l16) * DM + quad * 8];

    float4v acc[3];
#pragma unroll
    for (int i = 0; i < 3; i++) acc[i] = (float4v)(0.f);

    // pipeline stage: current regs
    float4v a0 = *reinterpret_cast<const float4v*>(xp);
    float4v a1 = *reinterpret_cast<const float4v*>(xp + 4);
    short8 b0 = load8(W0);
    short8 b1 = load8(W0 + 16 * DM);
    short8 b2 = load8(W0 + 32 * DM);

    for (int k0 = 0; k0 < DM - 32; k0 += 32) {
        // prefetch next k-step
        float4v na0 = *reinterpret_cast<const float4v*>(xp + k0 + 32);
        float4v na1 = *reinterpret_cast<const float4v*>(xp + k0 + 36);
        short8 nb0 = load8(W0 + k0 + 32);
        short8 nb1 = load8(W0 + 16 * DM + k0 + 32);
        short8 nb2 = load8(W0 + 32 * DM + k0 + 32);
        // compute current
        short8 a = pack8(a0, a1);
        acc[0] = __builtin_amdgcn_mfma_f32_16x16x32_bf16(a, b0, acc[0], 0, 0, 0);
        acc[1] = __builtin_amdgcn_mfma_f32_16x16x32_bf16(a, b1, acc[1], 0, 0, 0);
        acc[2] = __builtin_amdgcn_mfma_f32_16x16x32_bf16(a, b2, acc[2], 0, 0, 0);
        a0 = na0; a1 = na1; b0 = nb0; b1 = nb1; b2 = nb2;
    }
    {   // final k-step
        short8 a = pack8(a0, a1);
        acc[0] = __builtin_amdgcn_mfma_f32_16x16x32_bf16(a, b0, acc[0], 0, 0, 0);
        acc[1] = __builtin_amdgcn_mfma_f32_16x16x32_bf16(a, b1, acc[1], 0, 0, 0);
        acc[2] = __builtin_amdgcn_mfma_f32_16x16x32_bf16(a, b2, acc[2], 0, 0, 0);
    }

    // epilogue: Q/K direct; V -> LDS transpose tile
#pragma unroll
    for (int nt = 0; nt < 3; nt++) {
        const int cc = 48 * colq + 16 * nt + l16;          // 0..191
#pragma unroll
        for (int r = 0; r < 4; r++) {
            const int tl = 16 * half + quad * 4 + r;       // local row 0..31
            const int i  = row0 + tl;                      // global row b*T+t
            bf16 hv = __float2bfloat16(acc[nt][r]);
            if (cc < 64) {
                Qb[(size_t)i * DH + cc] = hv;
            } else if (cc < 128) {
                Kb[(size_t)i * DH + (cc - 64)] = hv;
            } else {
                Vls[cc - 128][tl] = hv;
            }
        }
    }
    __syncthreads();
    {   // coalesced Vt store: thread -> (d = tid>>3, 4 t-values)
        const int d  = threadIdx.x >> 3;
        const int u  = threadIdx.x & 7;
        const int b_ = row0 >> 12;
        const int t0 = row0 & (TT - 1);
        short4v sv;
#pragma unroll
        for (int q = 0; q < 4; q++)
            sv[q] = (short)__bfloat16_as_ushort(Vls[d][4 * u + q]);
        *reinterpret_cast<short4v*>(&Vt[((size_t)b_ * DH + d) * TT + t0 + 4 * u]) = sv;
    }
}

// ---------------------------------------------------------------------------
// Kernel 2: flash causal attention, S^T formulation, batched load issue.
// Block = 256 thr = 4 waves = 4 KV streams over the same 16 q-rows.
// Per 64-j iteration: ALL loads (8 K b128 + 16 V 8B) issued into registers up
// front -> one memory latency per iteration. P^T regs feed 16x16x16bf16_1k
// directly (no LDS round-trip). Merge via padded LDS at the end.
// Grid 1024 = 4 batch x 256 q-tiles, big/small paired remap.
// ---------------------------------------------------------------------------
__global__ __launch_bounds__(256, 4) void attn(
    const bf16* __restrict__ Qb, const bf16* __restrict__ Kb,
    const bf16* __restrict__ Vt, const float* __restrict__ rel,
    float* __restrict__ out)
{
    __shared__ float s_rel[NRE];
    __shared__ float m_sh[4][16], l_sh[4][16];
    __shared__ float O_sh[4][16][68];    // pad 64->68: conflict-free

    const int strm  = threadIdx.x >> 6;  // 0..3: KV stream
    const int lane  = threadIdx.x & 63;
    const int quad  = lane >> 4;
    const int l16   = lane & 15;
    const int batch = blockIdx.x & 3;
    const int b2    = blockIdx.x >> 2;                  // 0..255
    const int t     = (b2 < 128) ? b2 : (383 - b2);     // pair big+small on CU
    const int q0    = t * 16;

    if (threadIdx.x < NRE) s_rel[threadIdx.x] = rel[threadIdx.x];
    __syncthreads();
    const float rel0 = s_rel[0];

    const size_t bbase = (size_t)batch * TT;
    const bf16* vbase  = Vt + (size_t)batch * DH * TT;
    const int i_row = q0 + l16;          // this lane's q row

    // Q B-fragments (n = i on l16), k = quad*8.. for 16x16x32
    short8 bq0, bq1;
    {
        const bf16* qp = &Qb[(bbase + i_row) * DH];
        bq0 = load8(qp + quad * 8);
        bq1 = load8(qp + 32 + quad * 8);
    }

    float4v o[4];                        // o[dt][r]: O[i=l16][d=16dt+4quad+r]
#pragma unroll
    for (int dt = 0; dt < 4; dt++) o[dt] = (float4v)(0.f);
    float m_st = -1e30f, l_st = 0.f;

    for (int j0 = 64 * strm; j0 < q0 + 16; j0 += 256) {
        // ---- batch-issue ALL loads for this tile ----
        short8 ka[8];
#pragma unroll
        for (int nt = 0; nt < 4; nt++) {
            const bf16* kp = &Kb[(bbase + j0 + 16 * nt + l16) * DH];
            ka[2 * nt]     = load8(kp + quad * 8);
            ka[2 * nt + 1] = load8(kp + 32 + quad * 8);
        }
        short4v va[4][4];                // [nt][dt]
#pragma unroll
        for (int nt = 0; nt < 4; nt++)
#pragma unroll
            for (int dt = 0; dt < 4; dt++)
                va[nt][dt] = *reinterpret_cast<const short4v*>(
                    &vbase[(size_t)(16 * dt + l16) * TT + j0 + 16 * nt + 4 * quad]);

        // ---- S^T = K Q^T : st[nt] rows j=j0+16nt+4quad+r, cols i=l16 ----
        float4v st[4];
#pragma unroll
        for (int nt = 0; nt < 4; nt++) st[nt] = (float4v)(0.f);
#pragma unroll
        for (int nt = 0; nt < 4; nt++) {
            st[nt] = __builtin_amdgcn_mfma_f32_16x16x32_bf16(ka[2 * nt],     bq0, st[nt], 0, 0, 0);
            st[nt] = __builtin_amdgcn_mfma_f32_16x16x32_bf16(ka[2 * nt + 1], bq1, st[nt], 0, 0, 0);
        }

        // ---- scale + bias + causal mask ----
        float mcur = -1e30f;
        if (j0 + 71 <= q0) {             // interior: no mask, bias = rel[0]
#pragma unroll
            for (int nt = 0; nt < 4; nt++)
#pragma unroll
                for (int r = 0; r < 4; r++) {
                    float v = st[nt][r] * 0.125f + rel0;
                    st[nt][r] = v;
                    mcur = fmaxf(mcur, v);
                }
        } else {
#pragma unroll
            for (int nt = 0; nt < 4; nt++) {
                const int jb = j0 + 16 * nt + 4 * quad;
#pragma unroll
                for (int r = 0; r < 4; r++) {
                    const int d = jb + r - i_row;
                    int idx = d + 8;
                    idx = idx < 0 ? 0 : (idx > 16 ? 16 : idx);
                    float v = st[nt][r] * 0.125f + s_rel[idx];
                    v = (d > 0) ? -1e30f : v;
                    st[nt][r] = v;
                    mcur = fmaxf(mcur, v);
                }
            }
        }

        // ---- row max: 2 shfls ----
        mcur = fmaxf(mcur, __shfl_xor(mcur, 16, 64));
        mcur = fmaxf(mcur, __shfl_xor(mcur, 32, 64));

        const float mn = fmaxf(m_st, mcur);
        const float alpha = __expf(m_st - mn);
        m_st = mn;

        float lsum = 0.f;
        short4v pb[4];                   // P^T bf16: B-operand of 16x16x16_1k
#pragma unroll
        for (int nt = 0; nt < 4; nt++)
#pragma unroll
            for (int r = 0; r < 4; r++) {
                const float e = __expf(st[nt][r] - mn);
                lsum += e;
                pb[nt][r] = bfbits(e);
            }
        lsum += __shfl_xor(lsum, 16, 64);
        lsum += __shfl_xor(lsum, 32, 64);
        l_st = l_st * alpha + lsum;

#pragma unroll
        for (int dt = 0; dt < 4; dt++)
#pragma unroll
            for (int r = 0; r < 4; r++) o[dt][r] *= alpha;

        // ---- O += V^T P ----
#pragma unroll
        for (int nt = 0; nt < 4; nt++)
#pragma unroll
            for (int dt = 0; dt < 4; dt++)
                o[dt] = __builtin_amdgcn_mfma_f32_16x16x16bf16_1k(va[nt][dt], pb[nt], o[dt], 0, 0, 0);
    }

    // ---- publish per-stream partials ----
    if (quad == 0) {
        m_sh[strm][l16] = m_st;
        l_sh[strm][l16] = l_st;
    }
#pragma unroll
    for (int dt = 0; dt < 4; dt++)
        *reinterpret_cast<float4v*>(&O_sh[strm][l16][16 * dt + 4 * quad]) = o[dt];

    __syncthreads();

    // ---- merge 4 streams: 16 rows x 64 cols, 256 threads -> 4 each ----
    for (int idx = threadIdx.x; idx < 16 * 64; idx += 256) {
        const int row = idx >> 6;
        const int c   = idx & 63;
        float M = m_sh[0][row];
#pragma unroll
        for (int s2 = 1; s2 < 4; s2++) M = fmaxf(M, m_sh[s2][row]);
        float L = 0.f, acc = 0.f;
#pragma unroll
        for (int s2 = 0; s2 < 4; s2++) {
            const float e = __expf(m_sh[s2][row] - M);
            L   += l_sh[s2][row] * e;
            acc += O_sh[s2][row][c] * e;
        }
        out[(bbase + q0 + row) * DH + c] = acc / L;
    }
}

// ---------------------------------------------------------------------------
extern "C" void kernel_launch(void* const* d_in, const int* in_sizes, int n_in,
                              void* d_out, int out_size, void* d_ws, size_t ws_size,
                              hipStream_t stream)
{
    const float* x   = (const float*)d_in[0];
    const float* Wq  = (const float*)d_in[1];
    const float* Wk  = (const float*)d_in[2];
    const float* Wv  = (const float*)d_in[3];
    const float* rel = (const float*)d_in[4];
    float* out = (float*)d_out;

    bf16* Qb = (bf16*)d_ws;                       // [B*T, 64] bf16
    bf16* Kb = Qb + (size_t)BT * TT * DH;         // [B*T, 64] bf16
    bf16* Vt = Kb + (size_t)BT * TT * DH;         // [B, 64, T] bf16
    bf16* Wb = Vt + (size_t)BT * TT * DH;         // [192, 1024] bf16

    w_prep<<<192, 256, 0, stream>>>(Wq, Wk, Wv, Wb);
    qkv_gemm<<<512, 512, 0, stream>>>(x, Wb, Qb, Kb, Vt);
    attn<<<1024, 256, 0, stream>>>(Qb, Kb, Vt, rel, out);
}

// Round 6
// 203.313 us; speedup vs baseline: 1.2986x; 1.2986x over previous
//
#include <hip/hip_runtime.h>
#include <hip/hip_bf16.h>

#define BT 4
#define TT 4096
#define TTP 4128  // Vt row stride: +32 elem (64B) breaks L1 set aliasing
#define DM 1024
#define DH 64
#define NRE 17   // 2*MAX_REL+1
#define BKQ 128  // f32 k-chunk in qkv_gemm
#define LOG2E 1.4426950408889634f

using bf16 = __hip_bfloat16;
typedef __attribute__((ext_vector_type(8))) short short8;
typedef __attribute__((ext_vector_type(4))) short short4v;
typedef __attribute__((ext_vector_type(4))) float float4v;

static __device__ __forceinline__ short8 load8(const bf16* p) {
    return *reinterpret_cast<const short8*>(p);
}
static __device__ __forceinline__ short bfbits(float x) {
    return (short)__bfloat16_as_ushort(__float2bfloat16(x));
}
static __device__ __forceinline__ short8 pack8(float4v a, float4v b) {
    short8 r;
    r[0] = bfbits(a[0]); r[1] = bfbits(a[1]); r[2] = bfbits(a[2]); r[3] = bfbits(a[3]);
    r[4] = bfbits(b[0]); r[5] = bfbits(b[1]); r[6] = bfbits(b[2]); r[7] = bfbits(b[3]);
    return r;
}
// async global->LDS, 16B/lane; LDS dest = wave-uniform base + lane*16
static __device__ __forceinline__ void gload_lds16(const float* g, float* l) {
    __builtin_amdgcn_global_load_lds(
        (const __attribute__((address_space(1))) void*)g,
        (__attribute__((address_space(3))) void*)l, 16, 0, 0);
}

// ---------------------------------------------------------------------------
// Kernel 0: W prep — concat Wq|Wk|Wv (192x1024) f32 -> bf16 once.
// ---------------------------------------------------------------------------
__global__ __launch_bounds__(256) void w_prep(
    const float* __restrict__ Wq, const float* __restrict__ Wk,
    const float* __restrict__ Wv, bf16* __restrict__ Wb)
{
    const int row = blockIdx.x;          // 0..191
    const float* src = (row < 64) ? &Wq[(size_t)row * DM]
                     : (row < 128) ? &Wk[(size_t)(row - 64) * DM]
                                   : &Wv[(size_t)(row - 128) * DM];
    float4v v = reinterpret_cast<const float4v*>(src)[threadIdx.x];
    short4v s;
    s[0] = bfbits(v[0]); s[1] = bfbits(v[1]); s[2] = bfbits(v[2]); s[3] = bfbits(v[3]);
    *reinterpret_cast<short4v*>(&Wb[(size_t)row * DM + 4 * threadIdx.x]) = s;
}

// ---------------------------------------------------------------------------
// Kernel 1: QKV GEMM, m97 pattern. 512 blocks x 256 thr (4 waves).
// Block = 32 x-rows; wave = (16-row half) x (96-col half, 6 n-subtiles).
// x f32 staged via global_load_lds (double-buffered 2x16KB, HW queue holds
// the HBM stream); W batch-prefetched into regs per chunk BEFORE the stage
// issues (FIFO: W vmcnt waits don't drain the stage). V transposed through a
// small LDS tile for coalesced padded-row stores.
// ---------------------------------------------------------------------------
__global__ __launch_bounds__(256, 2) void qkv_gemm(
    const float* __restrict__ x, const bf16* __restrict__ Wb,
    bf16* __restrict__ Qb, bf16* __restrict__ Kb, bf16* __restrict__ Vt)
{
    __shared__ float xs[2][32 * BKQ];    // 2 x 16 KB
    __shared__ bf16 Vls[64][34];

    const int w    = threadIdx.x >> 6;   // 0..3
    const int lane = threadIdx.x & 63;
    const int quad = lane >> 4;
    const int l16  = lane & 15;
    const int half = w & 1;
    const int colh = w >> 1;             // 0/1: 96-col half
    const int row0 = blockIdx.x * 32;

    float4v acc[6];
#pragma unroll
    for (int i = 0; i < 6; i++) acc[i] = (float4v)(0.f);

    // stage chunk c into xs[buf]: 16 segs of 2 rows (1 KB each), 4 per wave
    auto stage = [&](int c, int buf) {
#pragma unroll
        for (int i = 0; i < 4; i++) {
            const int seg = 4 * w + i;   // rows 2seg, 2seg+1
            gload_lds16(&x[(size_t)(row0 + 2 * seg + (lane >> 5)) * DM
                           + c * BKQ + (lane & 31) * 4],
                        &xs[buf][seg * 256]);
        }
    };

    stage(0, 0);

    for (int c = 0; c < DM / BKQ; c++) {
        const int buf = c & 1;
        __syncthreads();                 // stage(c) complete (vmcnt drained)

        // W batch for this chunk (issued BEFORE next stage -> waits stay short)
        short8 wreg[6][4];
#pragma unroll
        for (int nt = 0; nt < 6; nt++)
#pragma unroll
            for (int ks = 0; ks < 4; ks++)
                wreg[nt][ks] = load8(&Wb[(size_t)(96 * colh + 16 * nt + l16) * DM
                                         + c * BKQ + ks * 32 + quad * 8]);

        if (c + 1 < DM / BKQ) stage(c + 1, buf ^ 1);

#pragma unroll
        for (int ks = 0; ks < 4; ks++) {
            const float* ap = &xs[buf][(16 * half + l16) * BKQ + ks * 32 + quad * 8];
            short8 a = pack8(*reinterpret_cast<const float4v*>(ap),
                             *reinterpret_cast<const float4v*>(ap + 4));
#pragma unroll
            for (int nt = 0; nt < 6; nt++)
                acc[nt] = __builtin_amdgcn_mfma_f32_16x16x32_bf16(a, wreg[nt][ks], acc[nt], 0, 0, 0);
        }
    }

    // epilogue: Q/K direct; V -> LDS transpose tile
#pragma unroll
    for (int nt = 0; nt < 6; nt++) {
        const int cc = 96 * colh + 16 * nt + l16;          // 0..191
#pragma unroll
        for (int r = 0; r < 4; r++) {
            const int tl = 16 * half + quad * 4 + r;       // local row 0..31
            const int i  = row0 + tl;                      // global row b*T+t
            bf16 hv = __float2bfloat16(acc[nt][r]);
            if (cc < 64) {
                Qb[(size_t)i * DH + cc] = hv;
            } else if (cc < 128) {
                Kb[(size_t)i * DH + (cc - 64)] = hv;
            } else {
                Vls[cc - 128][tl] = hv;
            }
        }
    }
    __syncthreads();
    {   // coalesced Vt store: thread -> (d = tid>>2, 8 t-values = 16B)
        const int d  = threadIdx.x >> 2;
        const int u  = threadIdx.x & 3;
        const int b_ = row0 >> 12;
        const int t0 = row0 & (TT - 1);
        short8 sv;
#pragma unroll
        for (int q = 0; q < 8; q++)
            sv[q] = (short)__bfloat16_as_ushort(Vls[d][8 * u + q]);
        *reinterpret_cast<short8*>(&Vt[((size_t)b_ * DH + d) * TTP + t0 + 8 * u]) = sv;
    }
}

// ---------------------------------------------------------------------------
// Kernel 2: flash causal attention, S^T formulation, ping-pong prefetch.
// Block = 256 thr = 4 waves = 4 KV streams over the same 16 q-rows; next
// tile's K/V loads (depth-1 pipeline, 2x64 transient VGPRs, cap 256) fly
// during current tile's MFMA+softmax. exp2-domain softmax. Vt rows padded.
// Grid 1024 = 4 batch x 256 q-tiles, big/small paired remap.
// ---------------------------------------------------------------------------
__global__ __launch_bounds__(256, 2) void attn(
    const bf16* __restrict__ Qb, const bf16* __restrict__ Kb,
    const bf16* __restrict__ Vt, const float* __restrict__ rel,
    float* __restrict__ out)
{
    __shared__ float s_rel[NRE];
    __shared__ float m_sh[4][16], l_sh[4][16];
    __shared__ float O_sh[4][16][68];    // pad 64->68: conflict-free

    const int strm  = threadIdx.x >> 6;  // 0..3: KV stream
    const int lane  = threadIdx.x & 63;
    const int quad  = lane >> 4;
    const int l16   = lane & 15;
    const int batch = blockIdx.x & 3;
    const int b2    = blockIdx.x >> 2;                  // 0..255
    const int t     = (b2 < 128) ? b2 : (383 - b2);     // pair big+small
    const int q0    = t * 16;

    if (threadIdx.x < NRE) s_rel[threadIdx.x] = rel[threadIdx.x] * LOG2E;
    __syncthreads();
    const float rel0 = s_rel[0];
    const float SCL  = 0.125f * LOG2E;

    const size_t bbase = (size_t)batch * TT;
    const bf16* vbase  = Vt + (size_t)batch * DH * TTP;
    const int i_row = q0 + l16;          // this lane's q row

    short8 bq0, bq1;                     // Q B-fragments
    {
        const bf16* qp = &Qb[(bbase + i_row) * DH];
        bq0 = load8(qp + quad * 8);
        bq1 = load8(qp + 32 + quad * 8);
    }

    float4v o[4];                        // o[dt][r]: O[i=l16][d=16dt+4quad+r]
#pragma unroll
    for (int dt = 0; dt < 4; dt++) o[dt] = (float4v)(0.f);
    float m_st = -1e30f, l_st = 0.f;

    const int jend = q0 + 16;
    const int js   = 64 * strm;
    const int cnt  = (js < jend) ? (jend - js + 255) / 256 : 0;

    short8  ka[2][8];
    short4v va[2][4][4];

    auto loadKV = [&](int j, int s) {
#pragma unroll
        for (int nt = 0; nt < 4; nt++) {
            const bf16* kp = &Kb[(bbase + j + 16 * nt + l16) * DH];
            ka[s][2 * nt]     = load8(kp + quad * 8);
            ka[s][2 * nt + 1] = load8(kp + 32 + quad * 8);
        }
#pragma unroll
        for (int nt = 0; nt < 4; nt++)
#pragma unroll
            for (int dt = 0; dt < 4; dt++)
                va[s][nt][dt] = *reinterpret_cast<const short4v*>(
                    &vbase[(size_t)(16 * dt + l16) * TTP + j + 16 * nt + 4 * quad]);
    };

    auto compute = [&](int j0c, int s) {
        float4v st[4];
#pragma unroll
        for (int nt = 0; nt < 4; nt++) st[nt] = (float4v)(0.f);
#pragma unroll
        for (int nt = 0; nt < 4; nt++) {
            st[nt] = __builtin_amdgcn_mfma_f32_16x16x32_bf16(ka[s][2 * nt],     bq0, st[nt], 0, 0, 0);
            st[nt] = __builtin_amdgcn_mfma_f32_16x16x32_bf16(ka[s][2 * nt + 1], bq1, st[nt], 0, 0, 0);
        }

        float mcur = -1e30f;
        if (j0c + 71 <= q0) {            // interior: no mask, bias = rel[0]
#pragma unroll
            for (int nt = 0; nt < 4; nt++)
#pragma unroll
                for (int r = 0; r < 4; r++) {
                    float v = st[nt][r] * SCL + rel0;
                    st[nt][r] = v;
                    mcur = fmaxf(mcur, v);
                }
        } else {
#pragma unroll
            for (int nt = 0; nt < 4; nt++) {
                const int jb = j0c + 16 * nt + 4 * quad;
#pragma unroll
                for (int r = 0; r < 4; r++) {
                    const int d = jb + r - i_row;
                    int idx = d + 8;
                    idx = idx < 0 ? 0 : (idx > 16 ? 16 : idx);
                    float v = st[nt][r] * SCL + s_rel[idx];
                    v = (d > 0) ? -1e30f : v;
                    st[nt][r] = v;
                    mcur = fmaxf(mcur, v);
                }
            }
        }

        mcur = fmaxf(mcur, __shfl_xor(mcur, 16, 64));
        mcur = fmaxf(mcur, __shfl_xor(mcur, 32, 64));

        const float mn = fmaxf(m_st, mcur);
        const float alpha = exp2f(m_st - mn);
        m_st = mn;

        float lsum = 0.f;
        short4v pb[4];
#pragma unroll
        for (int nt = 0; nt < 4; nt++)
#pragma unroll
            for (int r = 0; r < 4; r++) {
                const float e = exp2f(st[nt][r] - mn);
                lsum += e;
                pb[nt][r] = bfbits(e);
            }
        lsum += __shfl_xor(lsum, 16, 64);
        lsum += __shfl_xor(lsum, 32, 64);
        l_st = l_st * alpha + lsum;

#pragma unroll
        for (int dt = 0; dt < 4; dt++)
#pragma unroll
            for (int r = 0; r < 4; r++) o[dt][r] *= alpha;

#pragma unroll
        for (int nt = 0; nt < 4; nt++)
#pragma unroll
            for (int dt = 0; dt < 4; dt++)
                o[dt] = __builtin_amdgcn_mfma_f32_16x16x16bf16_1k(va[s][nt][dt], pb[nt], o[dt], 0, 0, 0);
    };

    if (cnt > 0) {
        int jc = js, k = 0;
        loadKV(jc, 0);
        while (true) {
            if (k + 1 < cnt) loadKV(jc + 256, 1);
            compute(jc, 0);
            k++; jc += 256;
            if (k >= cnt) break;
            if (k + 1 < cnt) loadKV(jc + 256, 0);
            compute(jc, 1);
            k++; jc += 256;
            if (k >= cnt) break;
        }
    }

    // ---- publish per-stream partials ----
    if (quad == 0) {
        m_sh[strm][l16] = m_st;
        l_sh[strm][l16] = l_st;
    }
#pragma unroll
    for (int dt = 0; dt < 4; dt++)
        *reinterpret_cast<float4v*>(&O_sh[strm][l16][16 * dt + 4 * quad]) = o[dt];

    __syncthreads();

    // ---- merge 4 streams ----
    for (int idx = threadIdx.x; idx < 16 * 64; idx += 256) {
        const int row = idx >> 6;
        const int c   = idx & 63;
        float M = m_sh[0][row];
#pragma unroll
        for (int s2 = 1; s2 < 4; s2++) M = fmaxf(M, m_sh[s2][row]);
        float L = 0.f, acc = 0.f;
#pragma unroll
        for (int s2 = 0; s2 < 4; s2++) {
            const float e = exp2f(m_sh[s2][row] - M);
            L   += l_sh[s2][row] * e;
            acc += O_sh[s2][row][c] * e;
        }
        out[(bbase + q0 + row) * DH + c] = acc / L;
    }
}

// ---------------------------------------------------------------------------
extern "C" void kernel_launch(void* const* d_in, const int* in_sizes, int n_in,
                              void* d_out, int out_size, void* d_ws, size_t ws_size,
                              hipStream_t stream)
{
    const float* x   = (const float*)d_in[0];
    const float* Wq  = (const float*)d_in[1];
    const float* Wk  = (const float*)d_in[2];
    const float* Wv  = (const float*)d_in[3];
    const float* rel = (const float*)d_in[4];
    float* out = (float*)d_out;

    bf16* Qb = (bf16*)d_ws;                       // [B*T, 64] bf16
    bf16* Kb = Qb + (size_t)BT * TT * DH;         // [B*T, 64] bf16
    bf16* Vt = Kb + (size_t)BT * TT * DH;         // [B, 64, TTP] bf16 (padded)
    bf16* Wb = Vt + (size_t)BT * DH * TTP;        // [192, 1024] bf16

    w_prep<<<192, 256, 0, stream>>>(Wq, Wk, Wv, Wb);
    qkv_gemm<<<512, 256, 0, stream>>>(x, Wb, Qb, Kb, Vt);
    attn<<<1024, 256, 0, stream>>>(Qb, Kb, Vt, rel, out);
}

// Round 7
// 203.287 us; speedup vs baseline: 1.2987x; 1.0001x over previous
//
#include <hip/hip_runtime.h>
#include <hip/hip_bf16.h>

#define BT 4
#define TT 4096
#define TTP 4128  // Vt row stride: +64B breaks L1 set aliasing
#define DM 1024
#define DH 64
#define NRE 17   // 2*MAX_REL+1
#define BKQ 128  // f32 k-chunk in qkv_gemm
#define LOG2E 1.4426950408889634f

using bf16 = __hip_bfloat16;
typedef __attribute__((ext_vector_type(8))) short short8;
typedef __attribute__((ext_vector_type(4))) short short4v;
typedef __attribute__((ext_vector_type(4))) float float4v;

static __device__ __forceinline__ short8 load8(const bf16* p) {
    return *reinterpret_cast<const short8*>(p);
}
static __device__ __forceinline__ short bfbits(float x) {
    return (short)__bfloat16_as_ushort(__float2bfloat16(x));
}
static __device__ __forceinline__ short8 pack8(float4v a, float4v b) {
    short8 r;
    r[0] = bfbits(a[0]); r[1] = bfbits(a[1]); r[2] = bfbits(a[2]); r[3] = bfbits(a[3]);
    r[4] = bfbits(b[0]); r[5] = bfbits(b[1]); r[6] = bfbits(b[2]); r[7] = bfbits(b[3]);
    return r;
}
static __device__ __forceinline__ void gload_lds16(const float* g, float* l) {
    __builtin_amdgcn_global_load_lds(
        (const __attribute__((address_space(1))) void*)g,
        (__attribute__((address_space(3))) void*)l, 16, 0, 0);
}

// ---------------------------------------------------------------------------
// Kernel 0: W prep — concat Wq|Wk|Wv (192x1024) f32 -> bf16 once.
// ---------------------------------------------------------------------------
__global__ __launch_bounds__(256) void w_prep(
    const float* __restrict__ Wq, const float* __restrict__ Wk,
    const float* __restrict__ Wv, bf16* __restrict__ Wb)
{
    const int row = blockIdx.x;          // 0..191
    const float* src = (row < 64) ? &Wq[(size_t)row * DM]
                     : (row < 128) ? &Wk[(size_t)(row - 64) * DM]
                                   : &Wv[(size_t)(row - 128) * DM];
    float4v v = reinterpret_cast<const float4v*>(src)[threadIdx.x];
    short4v s;
    s[0] = bfbits(v[0]); s[1] = bfbits(v[1]); s[2] = bfbits(v[2]); s[3] = bfbits(v[3]);
    *reinterpret_cast<short4v*>(&Wb[(size_t)row * DM + 4 * threadIdx.x]) = s;
}

// ---------------------------------------------------------------------------
// Kernel 1: QKV GEMM. 1024 blocks x 256 thr (4 blocks/CU). Block = 16 x-rows;
// wave w = cols [48w,48w+48) (3 n-subtiles). x staged via global_load_lds
// (double-buffered 2x8KB) with XOR-swizzled 16B units (conflict-free b128
// reads, contiguous stage). sched_barriers keep issue order W-batch -> stage
// -> compute so W's vmcnt waits never drain the in-flight stage (FIFO).
// ---------------------------------------------------------------------------
__global__ __launch_bounds__(256, 4) void qkv_gemm(
    const float* __restrict__ x, const bf16* __restrict__ Wb,
    bf16* __restrict__ Qb, bf16* __restrict__ Kb, bf16* __restrict__ Vt)
{
    __shared__ float xs[2][16 * BKQ];    // 2 x 8 KB
    __shared__ bf16 Vls[64][18];         // V transpose tile (pad 16->18)

    const int w    = threadIdx.x >> 6;   // 0..3
    const int lane = threadIdx.x & 63;
    const int quad = lane >> 4;
    const int l16  = lane & 15;
    const int row0 = blockIdx.x * 16;

    float4v acc[3];
#pragma unroll
    for (int i = 0; i < 3; i++) acc[i] = (float4v)(0.f);

    // stage chunk c: 8 calls x 1KB (2 rows each); phys unit pu=(lane&31) in
    // row holds global unit pu^row  => reader XORs with its row.
    auto stage = [&](int c, int buf) {
#pragma unroll
        for (int i = 0; i < 2; i++) {
            const int s    = 2 * w + i;              // 0..7
            const int row  = 2 * s + (lane >> 5);    // 0..15
            const int ulog = (lane & 31) ^ row;
            gload_lds16(&x[(size_t)(row0 + row) * DM + c * BKQ + 4 * ulog],
                        &xs[buf][s * 256]);
        }
    };

    stage(0, 0);

    for (int c = 0; c < DM / BKQ; c++) {
        const int buf = c & 1;
        __syncthreads();                 // stage(c) landed; buf^1 free

        // W batch for this chunk (48 VGPR), issued first
        short8 wreg[3][4];
#pragma unroll
        for (int nt = 0; nt < 3; nt++)
#pragma unroll
            for (int ks = 0; ks < 4; ks++)
                wreg[nt][ks] = load8(&Wb[(size_t)(48 * w + 16 * nt + l16) * DM
                                         + c * BKQ + ks * 32 + quad * 8]);
        __builtin_amdgcn_sched_barrier(0);

        if (c + 1 < DM / BKQ) stage(c + 1, buf ^ 1);
        __builtin_amdgcn_sched_barrier(0);

#pragma unroll
        for (int ks = 0; ks < 4; ks++) {
            const int u0 = 8 * ks + 2 * quad;
            const float* p0 = &xs[buf][l16 * BKQ + 4 * (u0 ^ l16)];
            const float* p1 = &xs[buf][l16 * BKQ + 4 * ((u0 + 1) ^ l16)];
            short8 a = pack8(*reinterpret_cast<const float4v*>(p0),
                             *reinterpret_cast<const float4v*>(p1));
#pragma unroll
            for (int nt = 0; nt < 3; nt++)
                acc[nt] = __builtin_amdgcn_mfma_f32_16x16x32_bf16(a, wreg[nt][ks], acc[nt], 0, 0, 0);
        }
    }

    // epilogue: Q/K direct; V -> LDS transpose tile
#pragma unroll
    for (int nt = 0; nt < 3; nt++) {
        const int cc = 48 * w + 16 * nt + l16;             // 0..191
#pragma unroll
        for (int r = 0; r < 4; r++) {
            const int tl = quad * 4 + r;                   // local row 0..15
            const int i  = row0 + tl;                      // global row b*T+t
            bf16 hv = __float2bfloat16(acc[nt][r]);
            if (cc < 64) {
                Qb[(size_t)i * DH + cc] = hv;
            } else if (cc < 128) {
                Kb[(size_t)i * DH + (cc - 64)] = hv;
            } else {
                Vls[cc - 128][tl] = hv;
            }
        }
    }
    __syncthreads();
    {   // coalesced Vt store: d = tid>>2, 4 t-values (8B)
        const int d  = threadIdx.x >> 2;
        const int u  = threadIdx.x & 3;
        const int b_ = row0 >> 12;
        const int t0 = row0 & (TT - 1);
        short4v sv;
#pragma unroll
        for (int q = 0; q < 4; q++)
            sv[q] = (short)__bfloat16_as_ushort(Vls[d][4 * u + q]);
        *reinterpret_cast<short4v*>(&Vt[((size_t)b_ * DH + d) * TTP + t0 + 4 * u]) = sv;
    }
}

// ---------------------------------------------------------------------------
// Kernel 2: flash causal attention, S^T formulation. Block = 256 thr =
// 4 waves = 4 KV streams over the same 16 q-rows. Per 64-j tile: ALL K/V
// loads issued in one block, sched_barrier(0) pins them ahead of the
// consumer chain -> one memory latency per tile. exp2-domain softmax.
// Grid 1024 = 4 batch x 256 q-tiles, big/small paired remap. (256,3).
// ---------------------------------------------------------------------------
__global__ __launch_bounds__(256, 3) void attn(
    const bf16* __restrict__ Qb, const bf16* __restrict__ Kb,
    const bf16* __restrict__ Vt, const float* __restrict__ rel,
    float* __restrict__ out)
{
    __shared__ float s_rel[NRE];
    __shared__ float m_sh[4][16], l_sh[4][16];
    __shared__ float O_sh[4][16][68];    // pad 64->68: conflict-free

    const int strm  = threadIdx.x >> 6;  // 0..3: KV stream
    const int lane  = threadIdx.x & 63;
    const int quad  = lane >> 4;
    const int l16   = lane & 15;
    const int batch = blockIdx.x & 3;
    const int b2    = blockIdx.x >> 2;                  // 0..255
    const int t     = (b2 < 128) ? b2 : (383 - b2);     // pair big+small
    const int q0    = t * 16;

    if (threadIdx.x < NRE) s_rel[threadIdx.x] = rel[threadIdx.x] * LOG2E;
    __syncthreads();
    const float rel0 = s_rel[0];
    const float SCL  = 0.125f * LOG2E;

    const size_t bbase = (size_t)batch * TT;
    const bf16* vbase  = Vt + (size_t)batch * DH * TTP;
    const int i_row = q0 + l16;          // this lane's q row

    short8 bq0, bq1;                     // Q B-fragments
    {
        const bf16* qp = &Qb[(bbase + i_row) * DH];
        bq0 = load8(qp + quad * 8);
        bq1 = load8(qp + 32 + quad * 8);
    }

    float4v o[4];                        // o[dt][r]: O[i=l16][d=16dt+4quad+r]
#pragma unroll
    for (int dt = 0; dt < 4; dt++) o[dt] = (float4v)(0.f);
    float m_st = -1e30f, l_st = 0.f;

    for (int j0 = 64 * strm; j0 < q0 + 16; j0 += 256) {
        // ---- batch-issue ALL loads for this tile; pin with sched_barrier ----
        short8 ka[8];
#pragma unroll
        for (int nt = 0; nt < 4; nt++) {
            const bf16* kp = &Kb[(bbase + j0 + 16 * nt + l16) * DH];
            ka[2 * nt]     = load8(kp + quad * 8);
            ka[2 * nt + 1] = load8(kp + 32 + quad * 8);
        }
        short4v va[4][4];                // [nt][dt]
#pragma unroll
        for (int nt = 0; nt < 4; nt++)
#pragma unroll
            for (int dt = 0; dt < 4; dt++)
                va[nt][dt] = *reinterpret_cast<const short4v*>(
                    &vbase[(size_t)(16 * dt + l16) * TTP + j0 + 16 * nt + 4 * quad]);
        __builtin_amdgcn_sched_barrier(0);

        // ---- S^T = K Q^T ----
        float4v st[4];
#pragma unroll
        for (int nt = 0; nt < 4; nt++) st[nt] = (float4v)(0.f);
#pragma unroll
        for (int nt = 0; nt < 4; nt++) {
            st[nt] = __builtin_amdgcn_mfma_f32_16x16x32_bf16(ka[2 * nt],     bq0, st[nt], 0, 0, 0);
            st[nt] = __builtin_amdgcn_mfma_f32_16x16x32_bf16(ka[2 * nt + 1], bq1, st[nt], 0, 0, 0);
        }

        // ---- scale + bias + causal mask ----
        float mcur = -1e30f;
        if (j0 + 71 <= q0) {             // interior: no mask, bias = rel[0]
#pragma unroll
            for (int nt = 0; nt < 4; nt++)
#pragma unroll
                for (int r = 0; r < 4; r++) {
                    float v = st[nt][r] * SCL + rel0;
                    st[nt][r] = v;
                    mcur = fmaxf(mcur, v);
                }
        } else {
#pragma unroll
            for (int nt = 0; nt < 4; nt++) {
                const int jb = j0 + 16 * nt + 4 * quad;
#pragma unroll
                for (int r = 0; r < 4; r++) {
                    const int d = jb + r - i_row;
                    int idx = d + 8;
                    idx = idx < 0 ? 0 : (idx > 16 ? 16 : idx);
                    float v = st[nt][r] * SCL + s_rel[idx];
                    v = (d > 0) ? -1e30f : v;
                    st[nt][r] = v;
                    mcur = fmaxf(mcur, v);
                }
            }
        }

        mcur = fmaxf(mcur, __shfl_xor(mcur, 16, 64));
        mcur = fmaxf(mcur, __shfl_xor(mcur, 32, 64));

        const float mn = fmaxf(m_st, mcur);
        const float alpha = exp2f(m_st - mn);
        m_st = mn;

        float lsum = 0.f;
        short4v pb[4];                   // P^T: B-operand of 16x16x16_1k
#pragma unroll
        for (int nt = 0; nt < 4; nt++)
#pragma unroll
            for (int r = 0; r < 4; r++) {
                const float e = exp2f(st[nt][r] - mn);
                lsum += e;
                pb[nt][r] = bfbits(e);
            }
        lsum += __shfl_xor(lsum, 16, 64);
        lsum += __shfl_xor(lsum, 32, 64);
        l_st = l_st * alpha + lsum;

#pragma unroll
        for (int dt = 0; dt < 4; dt++)
#pragma unroll
            for (int r = 0; r < 4; r++) o[dt][r] *= alpha;

        // ---- O += V^T P ----
#pragma unroll
        for (int nt = 0; nt < 4; nt++)
#pragma unroll
            for (int dt = 0; dt < 4; dt++)
                o[dt] = __builtin_amdgcn_mfma_f32_16x16x16bf16_1k(va[nt][dt], pb[nt], o[dt], 0, 0, 0);
    }

    // ---- publish per-stream partials ----
    if (quad == 0) {
        m_sh[strm][l16] = m_st;
        l_sh[strm][l16] = l_st;
    }
#pragma unroll
    for (int dt = 0; dt < 4; dt++)
        *reinterpret_cast<float4v*>(&O_sh[strm][l16][16 * dt + 4 * quad]) = o[dt];

    __syncthreads();

    // ---- merge 4 streams ----
    for (int idx = threadIdx.x; idx < 16 * 64; idx += 256) {
        const int row = idx >> 6;
        const int c   = idx & 63;
        float M = m_sh[0][row];
#pragma unroll
        for (int s2 = 1; s2 < 4; s2++) M = fmaxf(M, m_sh[s2][row]);
        float L = 0.f, acc = 0.f;
#pragma unroll
        for (int s2 = 0; s2 < 4; s2++) {
            const float e = exp2f(m_sh[s2][row] - M);
            L   += l_sh[s2][row] * e;
            acc += O_sh[s2][row][c] * e;
        }
        out[(bbase + q0 + row) * DH + c] = acc / L;
    }
}

// ---------------------------------------------------------------------------
extern "C" void kernel_launch(void* const* d_in, const int* in_sizes, int n_in,
                              void* d_out, int out_size, void* d_ws, size_t ws_size,
                              hipStream_t stream)
{
    const float* x   = (const float*)d_in[0];
    const float* Wq  = (const float*)d_in[1];
    const float* Wk  = (const float*)d_in[2];
    const float* Wv  = (const float*)d_in[3];
    const float* rel = (const float*)d_in[4];
    float* out = (float*)d_out;

    bf16* Qb = (bf16*)d_ws;                       // [B*T, 64] bf16
    bf16* Kb = Qb + (size_t)BT * TT * DH;         // [B*T, 64] bf16
    bf16* Vt = Kb + (size_t)BT * TT * DH;         // [B, 64, TTP] bf16 (padded)
    bf16* Wb = Vt + (size_t)BT * DH * TTP;        // [192, 1024] bf16

    w_prep<<<192, 256, 0, stream>>>(Wq, Wk, Wv, Wb);
    qkv_gemm<<<1024, 256, 0, stream>>>(x, Wb, Qb, Kb, Vt);
    attn<<<1024, 256, 0, stream>>>(Qb, Kb, Vt, rel, out);
}

// Round 8
// 170.685 us; speedup vs baseline: 1.5468x; 1.1910x over previous
//
#include <hip/hip_runtime.h>
#include <hip/hip_bf16.h>

#define BT 4
#define TT 4096
#define DM 1024
#define DH 64
#define NRE 17
#define LOG2E 1.4426950408889634f

using bf16 = __hip_bfloat16;
typedef __attribute__((ext_vector_type(8))) short short8;
typedef __attribute__((ext_vector_type(4))) short short4v;
typedef __attribute__((ext_vector_type(4))) float float4v;

static __device__ __forceinline__ short8 load8(const bf16* p) {
    return *reinterpret_cast<const short8*>(p);
}
static __device__ __forceinline__ short bfbits(float x) {
    return (short)__bfloat16_as_ushort(__float2bfloat16(x));
}
static __device__ __forceinline__ short8 pack8(float4v a, float4v b) {
    short8 r;
    r[0] = bfbits(a[0]); r[1] = bfbits(a[1]); r[2] = bfbits(a[2]); r[3] = bfbits(a[3]);
    r[4] = bfbits(b[0]); r[5] = bfbits(b[1]); r[6] = bfbits(b[2]); r[7] = bfbits(b[3]);
    return r;
}
static __device__ __forceinline__ void gload_lds16(const void* g, void* l) {
    __builtin_amdgcn_global_load_lds(
        (const __attribute__((address_space(1))) void*)g,
        (__attribute__((address_space(3))) void*)l, 16, 0, 0);
}

// ===========================================================================
// Swizzled global layouts (16B units, one per lane, frag-major):
//  Kswz: unit U = ((b*64+tile)*8 + f)*64 + lane, f=2*nt+h, lane=quad*16+l16,
//        holds K[b][64*tile+16*nt+l16][32*h+8*quad+e] e=0..7.
//  Vswz: unit U = ((b*64+tile)*8 + 2*nt+dh)*64 + lane; bytes0-7 d=32*dh+l16,
//        bytes8-15 d=32*dh+16+l16, j=64*tile+16*nt+4*quad+e e=0..3 (Vt vals).
//  Wswz (bf16, XOR-swizzled, chunk=32 k): unit g=(c*96+pair)*8+slot,
//        l=slot^(pair&7), holds W[2*pair+(l>>2)][32*c+(l&3)*8+e].
// ===========================================================================

// ---------------------------------------------------------------------------
// Kernel 0: W prep — build Wswz from Wq|Wk|Wv (f32) once.  24576 units.
// ---------------------------------------------------------------------------
__global__ __launch_bounds__(256) void w_prep(
    const float* __restrict__ Wq, const float* __restrict__ Wk,
    const float* __restrict__ Wv, bf16* __restrict__ Wswz)
{
    const unsigned g = blockIdx.x * 256 + threadIdx.x;   // < 24576
    const unsigned c    = g / 768;
    const unsigned rem  = g - c * 768;
    const unsigned pair = rem >> 3;
    const unsigned slot = rem & 7;
    const unsigned l    = slot ^ (pair & 7);
    const unsigned row  = 2 * pair + (l >> 2);           // 0..191
    const unsigned k    = 32 * c + (l & 3) * 8;
    const float* src = (row < 64) ? &Wq[(size_t)row * DM + k]
                     : (row < 128) ? &Wk[(size_t)(row - 64) * DM + k]
                                   : &Wv[(size_t)(row - 128) * DM + k];
    float4v a = *reinterpret_cast<const float4v*>(src);
    float4v b = *reinterpret_cast<const float4v*>(src + 4);
    *reinterpret_cast<short8*>(&Wswz[(size_t)g * 8]) = pack8(a, b);
}

// ---------------------------------------------------------------------------
// Kernel 1: QKV GEMM.  256 blocks x 256 thr (1/CU).  Block = 64 x-rows, wave
// w = m-rows [16w,16w+16) x all 192 cols (12 n-tiles).  BK=32: x DMA-staged
// (XOR unit swizzle), W DMA-staged (identity copy of pre-swizzled Wswz),
// double-buffered m97 loop.  Epilogue: Q direct; K,V through LDS images ->
// coalesced 16B stores in Kswz/Vswz fragment order.
// ---------------------------------------------------------------------------
__global__ __launch_bounds__(256, 2) void qkv_gemm(
    const float* __restrict__ x, const bf16* __restrict__ Wswz,
    bf16* __restrict__ Qb, bf16* __restrict__ Kswz, bf16* __restrict__ Vswz)
{
    __shared__ float xs[2][64 * 32];     // 2 x 8 KB
    __shared__ short Wls[2][96 * 64];    // 2 x 12 KB (pair-major, swizzled)
    __shared__ short Kimg[4096];         // 8 KB fragment image
    __shared__ short Vimg[4096];         // 8 KB

    const int w    = threadIdx.x >> 6;   // 0..3
    const int lane = threadIdx.x & 63;
    const int quad = lane >> 4;
    const int l16  = lane & 15;
    const int row0 = blockIdx.x * 64;
    const int b_   = row0 >> 12;
    const int tile = (row0 & (TT - 1)) >> 6;

    float4v acc[12];
#pragma unroll
    for (int i = 0; i < 12; i++) acc[i] = (float4v)(0.f);

    auto stage = [&](int c, int p) {
        // x: 8 KB = 8 calls (2/wave); rows 8/call; unit XOR row&7
#pragma unroll
        for (int i = 0; i < 2; i++) {
            const int call = 2 * w + i;
            const int row  = call * 8 + (lane >> 3);
            const int ul   = (lane & 7) ^ (row & 7);
            gload_lds16(&x[(size_t)(row0 + row) * DM + c * 32 + ul * 4],
                        &xs[p][call * 256]);
        }
        // W: 12 KB = 12 calls (3/wave); identity copy (pre-swizzled)
#pragma unroll
        for (int i = 0; i < 3; i++) {
            const int call = 3 * w + i;
            gload_lds16(&Wswz[(size_t)c * 6144 + call * 512 + lane * 8],
                        &Wls[p][call * 512]);
        }
    };

    stage(0, 0);

    for (int c = 0; c < 32; c++) {
        const int p = c & 1;
        __syncthreads();                 // drain DMA(c); buf p^1 free
        if (c + 1 < 32) stage(c + 1, p ^ 1);

        const int R = 16 * w + l16;
        float4v a0 = *reinterpret_cast<const float4v*>(
            &xs[p][R * 32 + 4 * ((2 * quad) ^ (l16 & 7))]);
        float4v a1 = *reinterpret_cast<const float4v*>(
            &xs[p][R * 32 + 4 * ((2 * quad + 1) ^ (l16 & 7))]);
        short8 a = pack8(a0, a1);
#pragma unroll
        for (int nt = 0; nt < 12; nt++) {
            const int pair = 8 * nt + (l16 >> 1);
            const int phys = ((l16 & 1) * 4 + quad) ^ (l16 >> 1);
            short8 bfr = *reinterpret_cast<const short8*>(&Wls[p][pair * 64 + phys * 8]);
            acc[nt] = __builtin_amdgcn_mfma_f32_16x16x32_bf16(a, bfr, acc[nt], 0, 0, 0);
        }
    }

    // ---- epilogue ----
#pragma unroll
    for (int nt = 0; nt < 12; nt++) {
#pragma unroll
        for (int r = 0; r < 4; r++) {
            const short hb = bfbits(acc[nt][r]);
            if (nt < 4) {
                const int i = row0 + 16 * w + quad * 4 + r;
                Qb[(size_t)i * DH + 16 * nt + l16] = __hip_bfloat16_raw{(unsigned short)hb};
            } else if (nt < 8) {
                const int h  = (nt - 4) >> 1;
                const int qk = ((nt - 4) & 1) * 2 + (l16 >> 3);
                Kimg[((2 * w + h) * 64 + qk * 16 + 4 * quad + r) * 8 + (l16 & 7)] = hb;
            }
        }
        if (nt >= 8) {
            const int dh = (nt - 8) >> 1;
            const int h8 = (nt - 8) & 1;
            short4v sv;
#pragma unroll
            for (int r = 0; r < 4; r++) sv[r] = bfbits(acc[nt][r]);
            *reinterpret_cast<short4v*>(
                &Vimg[((2 * w + dh) * 64 + quad * 16 + l16) * 8 + h8 * 4]) = sv;
        }
    }
    __syncthreads();
    {   // coalesced swizzled stores: 512 units each, 2 per thread
        const size_t base = ((size_t)b_ * 64 + tile) * 4096;  // elems (512 units*8)
#pragma unroll
        for (int i = 0; i < 2; i++) {
            const int u = threadIdx.x + 256 * i;
            *reinterpret_cast<short8*>(&Kswz[base + (size_t)u * 8]) =
                *reinterpret_cast<const short8*>(&Kimg[u * 8]);
            *reinterpret_cast<short8*>(&Vswz[base + (size_t)u * 8]) =
                *reinterpret_cast<const short8*>(&Vimg[u * 8]);
        }
    }
}

// ---------------------------------------------------------------------------
// Kernel 2: flash causal attention.  512 blocks x 256 thr (2/CU, 8 waves/CU).
// Block = 32 q-rows; wave w = (qh = w&1) x (stream = w>>1).  Per 128-j pair
// of 64-tiles: K+V staged by DMA from fragment-ordered Kswz/Vswz (identity,
// contiguous), double-buffered in exactly 64 KB LDS; every fragment read is
// a contiguous-1KB ds_read_b128.  rel bias via __shfl register table.
// 2-stream merge reuses the LDS buffers after the loop.
// ---------------------------------------------------------------------------
__global__ __launch_bounds__(256, 2) void attn(
    const bf16* __restrict__ Qb, const bf16* __restrict__ Kswz,
    const bf16* __restrict__ Vswz, const float* __restrict__ rel,
    float* __restrict__ out)
{
    __shared__ short sbuf[2][16384];     // 64 KB exactly: [K s0|K s1|V s0|V s1]

    const int w     = threadIdx.x >> 6;  // 0..3
    const int lane  = threadIdx.x & 63;
    const int quad  = lane >> 4;
    const int l16   = lane & 15;
    const int qh    = w & 1;
    const int strm  = w >> 1;
    const int batch = blockIdx.x & 3;
    const int u     = blockIdx.x >> 2;                  // 0..127
    const int t     = (u < 64) ? u : (191 - u);         // pair (u,127-u) on CU
    const int q0    = 32 * t;

    const float SCL = 0.125f * LOG2E;
    const float relreg = (lane < NRE) ? rel[lane] * LOG2E : 0.f;
    const float rel0 = __shfl(relreg, 0, 64);

    const size_t bbase = (size_t)batch * TT;
    const int i_row = q0 + 16 * qh + l16;

    short8 bq0, bq1;
    {
        const bf16* qp = &Qb[(bbase + i_row) * DH];
        bq0 = load8(qp + quad * 8);
        bq1 = load8(qp + 32 + quad * 8);
    }

    float4v o[4];
#pragma unroll
    for (int dt = 0; dt < 4; dt++) o[dt] = (float4v)(0.f);
    float m_st = -1e30f, l_st = 0.f;

    const int J = (q0 + 32 + 63) >> 6;   // # 64-j tiles
    const int C = (J + 1) >> 1;          // # 128-j chunks

    auto stage = [&](int c1, int p) {
        const int T = 2 * c1 + (w & 1);
        if (T >= J) return;
        const bf16* g = ((w < 2) ? Kswz : Vswz) + ((size_t)(batch * 64 + T)) * 4096;
#pragma unroll
        for (int call = 0; call < 8; call++)
            gload_lds16(g + call * 512 + lane * 8, &sbuf[p][w * 4096 + call * 512]);
    };

    stage(0, 0);

    for (int c = 0; c < C; c++) {
        const int p = c & 1;
        __syncthreads();                 // drain DMA(c); buf p^1 free
        if (c + 1 < C) stage(c + 1, p ^ 1);

        const int T = 2 * c + strm;
        if (T < J) {
            const int js = 64 * T;
            const short* Kl = &sbuf[p][strm * 4096];
            const short* Vl = &sbuf[p][8192 + strm * 4096];

            // ---- S^T = K Q^T (fragment reads: contiguous 1KB each) ----
            float4v st[4];
#pragma unroll
            for (int nt = 0; nt < 4; nt++) st[nt] = (float4v)(0.f);
#pragma unroll
            for (int nt = 0; nt < 4; nt++) {
                short8 k0 = *reinterpret_cast<const short8*>(Kl + (2 * nt) * 512 + lane * 8);
                short8 k1 = *reinterpret_cast<const short8*>(Kl + (2 * nt + 1) * 512 + lane * 8);
                st[nt] = __builtin_amdgcn_mfma_f32_16x16x32_bf16(k0, bq0, st[nt], 0, 0, 0);
                st[nt] = __builtin_amdgcn_mfma_f32_16x16x32_bf16(k1, bq1, st[nt], 0, 0, 0);
            }

            // ---- scale + bias + causal ----
            float mcur = -1e30f;
            if (js + 71 <= q0 + 16 * qh) {   // interior
#pragma unroll
                for (int nt = 0; nt < 4; nt++)
#pragma unroll
                    for (int r = 0; r < 4; r++) {
                        float v = st[nt][r] * SCL + rel0;
                        st[nt][r] = v;
                        mcur = fmaxf(mcur, v);
                    }
            } else {
#pragma unroll
                for (int nt = 0; nt < 4; nt++) {
                    const int jb = js + 16 * nt + 4 * quad;
#pragma unroll
                    for (int r = 0; r < 4; r++) {
                        const int d = jb + r - i_row;
                        int idx = d + 8;
                        idx = idx < 0 ? 0 : (idx > 16 ? 16 : idx);
                        float v = st[nt][r] * SCL + __shfl(relreg, idx, 64);
                        v = (d > 0) ? -1e30f : v;
                        st[nt][r] = v;
                        mcur = fmaxf(mcur, v);
                    }
                }
            }

            mcur = fmaxf(mcur, __shfl_xor(mcur, 16, 64));
            mcur = fmaxf(mcur, __shfl_xor(mcur, 32, 64));

            const float mn = fmaxf(m_st, mcur);
            const float alpha = exp2f(m_st - mn);
            m_st = mn;

            float lsum = 0.f;
            short4v pb[4];
#pragma unroll
            for (int nt = 0; nt < 4; nt++)
#pragma unroll
                for (int r = 0; r < 4; r++) {
                    const float e = exp2f(st[nt][r] - mn);
                    lsum += e;
                    pb[nt][r] = bfbits(e);
                }
            lsum += __shfl_xor(lsum, 16, 64);
            lsum += __shfl_xor(lsum, 32, 64);
            l_st = l_st * alpha + lsum;

#pragma unroll
            for (int dt = 0; dt < 4; dt++)
#pragma unroll
                for (int r = 0; r < 4; r++) o[dt][r] *= alpha;

            // ---- O += V^T P ----
#pragma unroll
            for (int nt = 0; nt < 4; nt++) {
#pragma unroll
                for (int dh = 0; dh < 2; dh++) {
                    short8 vs = *reinterpret_cast<const short8*>(
                        Vl + (nt * 2 + dh) * 512 + lane * 8);
                    short4v lo, hi;
                    lo[0] = vs[0]; lo[1] = vs[1]; lo[2] = vs[2]; lo[3] = vs[3];
                    hi[0] = vs[4]; hi[1] = vs[5]; hi[2] = vs[6]; hi[3] = vs[7];
                    o[2 * dh]     = __builtin_amdgcn_mfma_f32_16x16x16bf16_1k(lo, pb[nt], o[2 * dh], 0, 0, 0);
                    o[2 * dh + 1] = __builtin_amdgcn_mfma_f32_16x16x16bf16_1k(hi, pb[nt], o[2 * dh + 1], 0, 0, 0);
                }
            }
        }
    }

    // ---- 2-stream merge (reuse LDS) ----
    __syncthreads();
    float* Osh = (float*)&sbuf[0][0];               // [s*2+qh][16 rows][68]
    float* mM  = Osh + 4 * 16 * 68;                 // [s*2+qh][16]
    float* lL  = mM + 64;

    const int slot = (strm * 2 + qh) * 16 + l16;
    if (quad == 0) { mM[slot] = m_st; lL[slot] = l_st; }
#pragma unroll
    for (int dt = 0; dt < 4; dt++)
        *reinterpret_cast<float4v*>(
            &Osh[((strm * 2 + qh) * 16 + l16) * 68 + 16 * dt + 4 * quad]) = o[dt];
    __syncthreads();

    for (int idx = threadIdx.x; idx < 32 * 64; idx += 256) {
        const int row = idx >> 6;                   // 0..31
        const int qh2 = row >> 4, lr = row & 15;
        const int c2  = idx & 63;
        const float m0 = mM[(0 * 2 + qh2) * 16 + lr];
        const float m1 = mM[(1 * 2 + qh2) * 16 + lr];
        const float M = fmaxf(m0, m1);
        const float e0 = exp2f(m0 - M), e1 = exp2f(m1 - M);
        const float L = lL[(0 * 2 + qh2) * 16 + lr] * e0 + lL[(1 * 2 + qh2) * 16 + lr] * e1;
        const float acc = Osh[((0 * 2 + qh2) * 16 + lr) * 68 + c2] * e0
                        + Osh[((1 * 2 + qh2) * 16 + lr) * 68 + c2] * e1;
        out[(bbase + q0 + row) * DH + c2] = acc / L;
    }
}

// ---------------------------------------------------------------------------
extern "C" void kernel_launch(void* const* d_in, const int* in_sizes, int n_in,
                              void* d_out, int out_size, void* d_ws, size_t ws_size,
                              hipStream_t stream)
{
    const float* x   = (const float*)d_in[0];
    const float* Wq  = (const float*)d_in[1];
    const float* Wk  = (const float*)d_in[2];
    const float* Wv  = (const float*)d_in[3];
    const float* rel = (const float*)d_in[4];
    float* out = (float*)d_out;

    bf16* Qb   = (bf16*)d_ws;                         // [B*T,64]        2 MB
    bf16* Kswz = Qb   + (size_t)BT * TT * DH;         // frag-ordered    2 MB
    bf16* Vswz = Kswz + (size_t)BT * TT * DH;         // frag-ordered    2 MB
    bf16* Wswz = Vswz + (size_t)BT * TT * DH;         // swizzled W    384 KB

    w_prep<<<96, 256, 0, stream>>>(Wq, Wk, Wv, Wswz);
    qkv_gemm<<<256, 256, 0, stream>>>(x, Wswz, Qb, Kswz, Vswz);
    attn<<<512, 256, 0, stream>>>(Qb, Kswz, Vswz, rel, out);
}

// Round 9
// 160.949 us; speedup vs baseline: 1.6404x; 1.0605x over previous
//
#include <hip/hip_runtime.h>
#include <hip/hip_bf16.h>

#define BT 4
#define TT 4096
#define DM 1024
#define DH 64
#define NRE 17
#define LOG2E 1.4426950408889634f

using bf16 = __hip_bfloat16;
typedef __attribute__((ext_vector_type(8))) short short8;
typedef __attribute__((ext_vector_type(4))) short short4v;
typedef __attribute__((ext_vector_type(4))) float float4v;

#define BC8(x) __builtin_bit_cast(short8, x)

static __device__ __forceinline__ short8 load8(const bf16* p) {
    return *reinterpret_cast<const short8*>(p);
}
static __device__ __forceinline__ short bfbits(float x) {
    return (short)__bfloat16_as_ushort(__float2bfloat16(x));
}
static __device__ __forceinline__ short8 pack8(float4v a, float4v b) {
    short8 r;
    r[0] = bfbits(a[0]); r[1] = bfbits(a[1]); r[2] = bfbits(a[2]); r[3] = bfbits(a[3]);
    r[4] = bfbits(b[0]); r[5] = bfbits(b[1]); r[6] = bfbits(b[2]); r[7] = bfbits(b[3]);
    return r;
}
static __device__ __forceinline__ void gload_lds16(const void* g, void* l) {
    __builtin_amdgcn_global_load_lds(
        (const __attribute__((address_space(1))) void*)g,
        (__attribute__((address_space(3))) void*)l, 16, 0, 0);
}
static __device__ __forceinline__ unsigned lds_addr(const void* p) {
    return (unsigned)(size_t)(const __attribute__((address_space(3))) void*)p;
}

// invisible-to-waitcnt-pass LDS fragment read (offset must be a literal string)
#define DSR(dst, addr, off) \
    asm volatile("ds_read_b128 %0, %1 offset:" off : "=v"(dst) : "v"(addr))

// ===========================================================================
// Swizzled global layouts (16B units, frag-major) — identical to round 8:
//  Kswz slab (32 j): unit = f*64+lane, f=2*nt+h (nt=16j-block, h=k-half),
//        lane=quad*16+l16 -> K[j=16nt+l16][k=32h+8quad+e].
//  Vswz slab (32 j): unit = (2nt+dh)*64+lane; bytes0-7 d=32dh+l16, 8-15 d+16,
//        j=16nt+4quad+e.
//  Wswz (per 32-k chunk c): unit=(c*96+pair)*8+slot, l=slot^(pair&7),
//        row=2pair+(l>>2), k=32c+(l&3)*8.
// ===========================================================================

__global__ __launch_bounds__(256) void w_prep(
    const float* __restrict__ Wq, const float* __restrict__ Wk,
    const float* __restrict__ Wv, bf16* __restrict__ Wswz)
{
    const unsigned g = blockIdx.x * 256 + threadIdx.x;   // < 24576
    const unsigned c    = g / 768;
    const unsigned rem  = g - c * 768;
    const unsigned pair = rem >> 3;
    const unsigned slot = rem & 7;
    const unsigned l    = slot ^ (pair & 7);
    const unsigned row  = 2 * pair + (l >> 2);
    const unsigned k    = 32 * c + (l & 3) * 8;
    const float* src = (row < 64) ? &Wq[(size_t)row * DM + k]
                     : (row < 128) ? &Wk[(size_t)(row - 64) * DM + k]
                                   : &Wv[(size_t)(row - 128) * DM + k];
    float4v a = *reinterpret_cast<const float4v*>(src);
    float4v b = *reinterpret_cast<const float4v*>(src + 4);
    *reinterpret_cast<short8*>(&Wswz[(size_t)g * 8]) = pack8(a, b);
}

// ---------------------------------------------------------------------------
// Kernel 1: QKV GEMM. 512 blocks x 256 thr (2 blocks/CU). Block = 32 rows;
// wave = (16-row half) x (96-col half). BK=64, m97 double-buffer via DMA;
// fragment reads via inline-asm ds_read_b128 (invisible to the waitcnt pass
// -> no conservative mid-chunk vmcnt drain; the pre-barrier drain provides
// the data guarantee). LDS = 16KB x + 48KB W = 64KB exactly.
// ---------------------------------------------------------------------------
__global__ __launch_bounds__(256, 2) void qkv_gemm(
    const float* __restrict__ x, const bf16* __restrict__ Wswz,
    bf16* __restrict__ Qb, bf16* __restrict__ Kswz, bf16* __restrict__ Vswz)
{
    __shared__ __align__(16) float xs[2][2048];   // 2 x 8 KB  [row(32)][unit(16)]
    __shared__ __align__(16) short Wls[2][12288]; // 2 x 24 KB (2 swz chunks)

    const int w    = threadIdx.x >> 6;
    const int lane = threadIdx.x & 63;
    const int quad = lane >> 4;
    const int l16  = lane & 15;
    const int half = w & 1;
    const int colh = w >> 1;
    const int row0 = blockIdx.x * 32;

    float4v acc[6];
#pragma unroll
    for (int i = 0; i < 6; i++) acc[i] = (float4v)(0.f);

    auto stage = [&](int c, int p) {
        // x: 8 calls (2/wave), 4 rows each, low-3-bit XOR unit swizzle
#pragma unroll
        for (int j = 0; j < 2; j++) {
            const int call = 2 * w + j;
            const int row  = 4 * call + (lane >> 4);
            const int pu   = lane & 15;
            const int gu   = (pu & 8) | ((pu ^ row) & 7);
            gload_lds16(&x[(size_t)(row0 + row) * DM + c * 64 + gu * 4],
                        &xs[p][call * 256]);
        }
        // W: 24 calls (6/wave), identity copy of chunks 2c,2c+1
#pragma unroll
        for (int j = 0; j < 6; j++) {
            const int call = 6 * w + j;
            gload_lds16(&Wswz[(size_t)(2 * c) * 6144 + call * 512 + lane * 8],
                        &Wls[p][call * 512]);
        }
    };

    const unsigned xlds = lds_addr(&xs[0][0]);
    const unsigned wlds = lds_addr(&Wls[0][0]);
    const int R        = 16 * half + l16;
    const int lo3_0    = (2 * quad)     ^ (R & 7);
    const int lo3_1    = (2 * quad + 1) ^ (R & 7);
    const int pairBase = 48 * colh + (l16 >> 1);
    const int physW    = ((l16 & 1) * 4 + quad) ^ ((l16 >> 1) & 7);

    stage(0, 0);

    for (int c = 0; c < 16; c++) {
        const int p = c & 1;
        __syncthreads();                      // drains stage(c) (pre-barrier vmcnt(0))
        if (c + 1 < 16) stage(c + 1, p ^ 1);

        const unsigned xb  = xlds + (unsigned)(p * 8192) + R * 64 * 4;
        const unsigned xa0 = xb + lo3_0 * 16;
        const unsigned xa1 = xb + lo3_1 * 16;
        const unsigned wa  = wlds + (unsigned)(p * 24576) + pairBase * 128 + physW * 16;

        float4v x00, x01, x10, x11;
        float4v w00, w01, w02, w03, w04, w05, w10, w11, w12, w13, w14, w15;
        DSR(x00, xa0, "0");   DSR(x10, xa0, "128");
        DSR(x01, xa1, "0");   DSR(x11, xa1, "128");
        DSR(w00, wa, "0");     DSR(w01, wa, "1024");  DSR(w02, wa, "2048");
        DSR(w03, wa, "3072");  DSR(w04, wa, "4096");  DSR(w05, wa, "5120");
        DSR(w10, wa, "12288"); DSR(w11, wa, "13312"); DSR(w12, wa, "14336");
        DSR(w13, wa, "15360"); DSR(w14, wa, "16384"); DSR(w15, wa, "17408");
        asm volatile("s_waitcnt lgkmcnt(0)"
            : "+v"(x00), "+v"(x01), "+v"(x10), "+v"(x11),
              "+v"(w00), "+v"(w01), "+v"(w02), "+v"(w03), "+v"(w04), "+v"(w05),
              "+v"(w10), "+v"(w11), "+v"(w12), "+v"(w13), "+v"(w14), "+v"(w15));

        short8 a0 = pack8(x00, x01);
        short8 a1 = pack8(x10, x11);
        acc[0] = __builtin_amdgcn_mfma_f32_16x16x32_bf16(a0, BC8(w00), acc[0], 0, 0, 0);
        acc[1] = __builtin_amdgcn_mfma_f32_16x16x32_bf16(a0, BC8(w01), acc[1], 0, 0, 0);
        acc[2] = __builtin_amdgcn_mfma_f32_16x16x32_bf16(a0, BC8(w02), acc[2], 0, 0, 0);
        acc[3] = __builtin_amdgcn_mfma_f32_16x16x32_bf16(a0, BC8(w03), acc[3], 0, 0, 0);
        acc[4] = __builtin_amdgcn_mfma_f32_16x16x32_bf16(a0, BC8(w04), acc[4], 0, 0, 0);
        acc[5] = __builtin_amdgcn_mfma_f32_16x16x32_bf16(a0, BC8(w05), acc[5], 0, 0, 0);
        acc[0] = __builtin_amdgcn_mfma_f32_16x16x32_bf16(a1, BC8(w10), acc[0], 0, 0, 0);
        acc[1] = __builtin_amdgcn_mfma_f32_16x16x32_bf16(a1, BC8(w11), acc[1], 0, 0, 0);
        acc[2] = __builtin_amdgcn_mfma_f32_16x16x32_bf16(a1, BC8(w12), acc[2], 0, 0, 0);
        acc[3] = __builtin_amdgcn_mfma_f32_16x16x32_bf16(a1, BC8(w13), acc[3], 0, 0, 0);
        acc[4] = __builtin_amdgcn_mfma_f32_16x16x32_bf16(a1, BC8(w14), acc[4], 0, 0, 0);
        acc[5] = __builtin_amdgcn_mfma_f32_16x16x32_bf16(a1, BC8(w15), acc[5], 0, 0, 0);
    }

    // ---- epilogue: Q direct; K/V through LDS images (alias xs) ----
    __syncthreads();
    short* Kimg = (short*)&xs[0][0];      // 4 KB (256 units)
    short* Vimg = Kimg + 2048;            // 4 KB
#pragma unroll
    for (int nt = 0; nt < 6; nt++) {
        const int cc = 96 * colh + 16 * nt + l16;          // 0..191
#pragma unroll
        for (int r = 0; r < 4; r++) {
            const int jl = 16 * half + 4 * quad + r;       // local row 0..31
            const short hb = bfbits(acc[nt][r]);
            if (cc < 64) {
                Qb[(size_t)(row0 + jl) * DH + cc] = __hip_bfloat16_raw{(unsigned short)hb};
            } else if (cc < 128) {
                const int k  = cc - 64;
                const int h  = k >> 5;
                const int q2 = (k & 31) >> 3;
                Kimg[((2 * half + h) * 64 + q2 * 16 + 4 * quad + r) * 8 + (k & 7)] = hb;
            } else {
                const int d  = cc - 128;
                const int dh = d >> 5;
                const int hi = (d >> 4) & 1;
                Vimg[((2 * half + dh) * 64 + quad * 16 + (d & 15)) * 8 + hi * 4 + r] = hb;
            }
        }
    }
    __syncthreads();
    {
        const int b_     = row0 >> 12;
        const int tile32 = (row0 & (TT - 1)) >> 5;
        const size_t base = ((size_t)(b_ * 512 + tile32 * 4)) * 512;  // elems
        const int u = threadIdx.x;                                    // 256 units
        *reinterpret_cast<short8*>(&Kswz[base + (size_t)u * 8]) =
            *reinterpret_cast<const short8*>(&Kimg[u * 8]);
        *reinterpret_cast<short8*>(&Vswz[base + (size_t)u * 8]) =
            *reinterpret_cast<const short8*>(&Vimg[u * 8]);
    }
}

// ---------------------------------------------------------------------------
// Kernel 2: flash causal attention — barrier-free wave-private pipeline.
// 512 blocks (4 batch x 128 q-tiles of 32 rows) x 256 thr, 2 blocks/CU.
// Wave = one KV stream (32-j tiles T ≡ w mod 4), handles BOTH 16-row halves
// (K/V staged once, used twice). Per tile: issue next tile's 8 DMA calls,
// s_waitcnt vmcnt(8) (builtin — recognized by the waitcnt pass), then asm
// ds_read_b128 fragments + tied lgkmcnt(0). No __syncthreads until merge.
// ---------------------------------------------------------------------------
__global__ __launch_bounds__(256, 2) void attn(
    const bf16* __restrict__ Qb, const bf16* __restrict__ Kswz,
    const bf16* __restrict__ Vswz, const float* __restrict__ rel,
    float* __restrict__ out)
{
    __shared__ __align__(16) short sbuf[32768];  // 64 KB: per wave 16 KB (2 bufs x [K 4K|V 4K])

    const int w     = threadIdx.x >> 6;
    const int lane  = threadIdx.x & 63;
    const int quad  = lane >> 4;
    const int l16   = lane & 15;
    const int batch = blockIdx.x & 3;
    const int u     = blockIdx.x >> 2;                  // 0..127
    const int t     = (u & 1) ? (127 - (u >> 1)) : (u >> 1);
    const int q0    = 32 * t;

    const float SCL = 0.125f * LOG2E;
    float relreg = 0.f;
    if (lane < NRE) relreg = rel[lane] * LOG2E;
    const float rel0 = __shfl(relreg, 0, 64);

    const size_t bbase = (size_t)batch * TT;

    short8 bq[2][2];
#pragma unroll
    for (int qh = 0; qh < 2; qh++) {
        const bf16* qp = &Qb[(bbase + q0 + 16 * qh + l16) * DH];
        bq[qh][0] = load8(qp + quad * 8);
        bq[qh][1] = load8(qp + 32 + quad * 8);
    }
    __builtin_amdgcn_s_waitcnt(0xF70);   // drain Q/rel so loop vmcnt counts only DMA

    float4v o[2][4];
#pragma unroll
    for (int qh = 0; qh < 2; qh++)
#pragma unroll
        for (int dt = 0; dt < 4; dt++) o[qh][dt] = (float4v)(0.f);
    float m_st[2] = {-1e30f, -1e30f}, l_st[2] = {0.f, 0.f};

    short* mybuf = &sbuf[w * 8192];
    const unsigned sbase = lds_addr(&sbuf[0]) + (unsigned)(w * 16384 + lane * 16);

    auto stageKV = [&](int T, int p) {
        const size_t gb = ((size_t)(batch * 512 + T * 4)) * 512;   // elems
        short* dK = mybuf + p * 4096;
#pragma unroll
        for (int j = 0; j < 4; j++)
            gload_lds16(&Kswz[gb + j * 512 + lane * 8], dK + j * 512);
#pragma unroll
        for (int j = 0; j < 4; j++)
            gload_lds16(&Vswz[gb + j * 512 + lane * 8], dK + 2048 + j * 512);
    };

    const int cnt = (t >= w) ? (((t - w) >> 2) + 1) : 0;
    if (cnt > 0) stageKV(w, 0);

    for (int k = 0; k < cnt; k++) {
        const int T = w + 4 * k;
        const int p = k & 1;
        if (k + 1 < cnt) {
            stageKV(w + 4 * (k + 1), p ^ 1);
            __builtin_amdgcn_s_waitcnt(0xF78);   // vmcnt(8): tile T landed
        } else {
            __builtin_amdgcn_s_waitcnt(0xF70);   // vmcnt(0)
        }

        const unsigned ab = sbase + (unsigned)(p * 8192);
        float4v kf0, kf1, kf2, kf3, vf0, vf1, vf2, vf3;
        DSR(kf0, ab, "0");    DSR(kf1, ab, "1024");
        DSR(kf2, ab, "2048"); DSR(kf3, ab, "3072");
        DSR(vf0, ab, "4096"); DSR(vf1, ab, "5120");
        DSR(vf2, ab, "6144"); DSR(vf3, ab, "7168");
        asm volatile("s_waitcnt lgkmcnt(0)"
            : "+v"(kf0), "+v"(kf1), "+v"(kf2), "+v"(kf3),
              "+v"(vf0), "+v"(vf1), "+v"(vf2), "+v"(vf3));

        const int js = 32 * T;
#pragma unroll
        for (int qh = 0; qh < 2; qh++) {
            float4v st[2];
            st[0] = (float4v)(0.f); st[1] = (float4v)(0.f);
            st[0] = __builtin_amdgcn_mfma_f32_16x16x32_bf16(BC8(kf0), bq[qh][0], st[0], 0, 0, 0);
            st[0] = __builtin_amdgcn_mfma_f32_16x16x32_bf16(BC8(kf1), bq[qh][1], st[0], 0, 0, 0);
            st[1] = __builtin_amdgcn_mfma_f32_16x16x32_bf16(BC8(kf2), bq[qh][0], st[1], 0, 0, 0);
            st[1] = __builtin_amdgcn_mfma_f32_16x16x32_bf16(BC8(kf3), bq[qh][1], st[1], 0, 0, 0);

            const int i_row = q0 + 16 * qh + l16;
            float mcur = -1e30f;
            if (js + 40 <= q0 + 16 * qh) {       // interior: bias=rel0, no mask
#pragma unroll
                for (int n = 0; n < 2; n++)
#pragma unroll
                    for (int r = 0; r < 4; r++) {
                        float v = st[n][r] * SCL + rel0;
                        st[n][r] = v;
                        mcur = fmaxf(mcur, v);
                    }
            } else {
#pragma unroll
                for (int n = 0; n < 2; n++) {
                    const int jb = js + 16 * n + 4 * quad;
#pragma unroll
                    for (int r = 0; r < 4; r++) {
                        const int d = jb + r - i_row;
                        int idx = d + 8;
                        idx = idx < 0 ? 0 : (idx > 16 ? 16 : idx);
                        float v = st[n][r] * SCL + __shfl(relreg, idx, 64);
                        v = (d > 0) ? -1e30f : v;
                        st[n][r] = v;
                        mcur = fmaxf(mcur, v);
                    }
                }
            }

            mcur = fmaxf(mcur, __shfl_xor(mcur, 16, 64));
            mcur = fmaxf(mcur, __shfl_xor(mcur, 32, 64));

            const float mn = fmaxf(m_st[qh], mcur);
            const float alpha = exp2f(m_st[qh] - mn);
            m_st[qh] = mn;

            float lsum = 0.f;
            short4v pb[2];
#pragma unroll
            for (int n = 0; n < 2; n++)
#pragma unroll
                for (int r = 0; r < 4; r++) {
                    const float e = exp2f(st[n][r] - mn);
                    lsum += e;
                    pb[n][r] = bfbits(e);
                }
            lsum += __shfl_xor(lsum, 16, 64);
            lsum += __shfl_xor(lsum, 32, 64);
            l_st[qh] = l_st[qh] * alpha + lsum;

#pragma unroll
            for (int dt = 0; dt < 4; dt++)
#pragma unroll
                for (int r = 0; r < 4; r++) o[qh][dt][r] *= alpha;

#pragma unroll
            for (int n = 0; n < 2; n++) {
#pragma unroll
                for (int dh = 0; dh < 2; dh++) {
                    const short8 vs = BC8((dh == 0) ? ((n == 0) ? vf0 : vf2)
                                                    : ((n == 0) ? vf1 : vf3));
                    short4v lo, hi;
                    lo[0] = vs[0]; lo[1] = vs[1]; lo[2] = vs[2]; lo[3] = vs[3];
                    hi[0] = vs[4]; hi[1] = vs[5]; hi[2] = vs[6]; hi[3] = vs[7];
                    o[qh][2 * dh]     = __builtin_amdgcn_mfma_f32_16x16x16bf16_1k(lo, pb[n], o[qh][2 * dh], 0, 0, 0);
                    o[qh][2 * dh + 1] = __builtin_amdgcn_mfma_f32_16x16x16bf16_1k(hi, pb[n], o[qh][2 * dh + 1], 0, 0, 0);
                }
            }
        }
    }

    // ---- merge 4 streams (single barrier; reuse sbuf) ----
    __syncthreads();
    float* Osh = (float*)&sbuf[0];         // [strm*32+row][68]
    float* mM  = Osh + 4 * 32 * 68;        // 128
    float* lL  = mM + 128;

#pragma unroll
    for (int qh = 0; qh < 2; qh++) {
        const int row = w * 32 + 16 * qh + l16;
        if (quad == 0) { mM[row] = m_st[qh]; lL[row] = l_st[qh]; }
#pragma unroll
        for (int dt = 0; dt < 4; dt++)
            *reinterpret_cast<float4v*>(&Osh[row * 68 + 16 * dt + 4 * quad]) = o[qh][dt];
    }
    __syncthreads();

    for (int idx = threadIdx.x; idx < 32 * 64; idx += 256) {
        const int row = idx >> 6;
        const int col = idx & 63;
        float M = mM[row];
#pragma unroll
        for (int s = 1; s < 4; s++) M = fmaxf(M, mM[s * 32 + row]);
        float L = 0.f, acc = 0.f;
#pragma unroll
        for (int s = 0; s < 4; s++) {
            const float e = exp2f(mM[s * 32 + row] - M);
            L   += lL[s * 32 + row] * e;
            acc += Osh[(s * 32 + row) * 68 + col] * e;
        }
        out[(bbase + q0 + row) * DH + col] = acc / L;
    }
}

// ---------------------------------------------------------------------------
extern "C" void kernel_launch(void* const* d_in, const int* in_sizes, int n_in,
                              void* d_out, int out_size, void* d_ws, size_t ws_size,
                              hipStream_t stream)
{
    const float* x   = (const float*)d_in[0];
    const float* Wq  = (const float*)d_in[1];
    const float* Wk  = (const float*)d_in[2];
    const float* Wv  = (const float*)d_in[3];
    const float* rel = (const float*)d_in[4];
    float* out = (float*)d_out;

    bf16* Qb   = (bf16*)d_ws;                         // [B*T,64]        2 MB
    bf16* Kswz = Qb   + (size_t)BT * TT * DH;         // frag-ordered    2 MB
    bf16* Vswz = Kswz + (size_t)BT * TT * DH;         // frag-ordered    2 MB
    bf16* Wswz = Vswz + (size_t)BT * TT * DH;         // swizzled W    384 KB

    w_prep<<<96, 256, 0, stream>>>(Wq, Wk, Wv, Wswz);
    qkv_gemm<<<512, 256, 0, stream>>>(x, Wswz, Qb, Kswz, Vswz);
    attn<<<512, 256, 0, stream>>>(Qb, Kswz, Vswz, rel, out);
}